// Round 1
// baseline (1990.903 us; speedup 1.0000x reference)
//
#include <hip/hip_runtime.h>
#include <math.h>

#define T_LEN 32768
#define NCH   16
#define NB    8
#define NWIN  252
#define NF    64      // bins f=1..64 (f=0 excluded by masks)
#define NPAIR 136     // upper triangle incl diag of 16x16
#define NBAND 6
#define WSAMP 608     // samples per channel needed per window

// ---------------------------------------------------------------------------
// Kernel 1: fused STFT + CSD + band averaging. One block per (b, w).
// band[b][w][k][c][d]  (full symmetric 16x16 per band) -> workspace
// ---------------------------------------------------------------------------
__global__ __launch_bounds__(256) void csd_band_kernel(const float* __restrict__ x,
                                                       float* __restrict__ band)
{
    const int w   = blockIdx.x;   // 0..251
    const int b   = blockIdx.y;   // 0..7
    const int tid = threadIdx.x;

    __shared__ float xin[NCH][609];     // 608 samples + pad (bank spread)
    __shared__ float xwin[NCH][132];    // windowed frame (pad 132: 4-ch float4 reads conflict-free)
    __shared__ float Xre[NCH][NF];
    __shared__ float Xim[NCH][NF];
    __shared__ float csd_re[NPAIR][65]; // 65: conflict-free stride
    __shared__ float csd_im[NPAIR][65];
    __shared__ float win[128];
    __shared__ unsigned char pc_[NPAIR], pd_[NPAIR];

    const double PI = 3.14159265358979323846;

    // Hann window / wnorm.  sum(w^2) = 47.625 exactly (analytic).
    if (tid < 128) {
        double ang = 2.0 * PI * (double)tid / 127.0;
        double wv  = 0.5 - 0.5 * cos(ang);
        win[tid] = (float)(wv / sqrt(47.625));
    }
    if (tid == 0) {
        int p = 0;
        for (int c = 0; c < 16; ++c)
            for (int d = c; d < 16; ++d) { pc_[p] = (unsigned char)c; pd_[p] = (unsigned char)d; ++p; }
    }
    for (int i = tid; i < NPAIR * 65; i += 256) {
        (&csd_re[0][0])[i] = 0.f;
        (&csd_im[0][0])[i] = 0.f;
    }
    // stage input: channels x 608 samples starting at t0 = w*128
    {
        const float* xb = x + (size_t)(b * NCH) * T_LEN + (size_t)w * 128;
        for (int c = 0; c < NCH; ++c)
            for (int t = tid; t < WSAMP; t += 256)
                xin[c][t] = xb[(size_t)c * T_LEN + t];
    }

    // per-thread DFT assignment: one frequency, 4 channels {c0, c0+4, c0+8, c0+12}
    const int   fi0 = tid & 63;
    const int   f   = fi0 + 1;
    const int   c0  = tid >> 6;
    float wr, wi;
    {
        double ang = -2.0 * PI * (double)f / 128.0;
        wr = (float)cos(ang);
        wi = (float)sin(ang);
    }

    __syncthreads();

    for (int s = 0; s < 16; ++s) {
        // build windowed frame for this s
        for (int i = tid; i < NCH * 128; i += 256) {
            int c = i >> 7, n = i & 127;
            xwin[c][n] = xin[c][s * 32 + n] * win[n];
        }
        __syncthreads();

        // direct DFT, incremental rotation re-seeded exactly every 32 samples
        float a0r = 0.f, a0i = 0.f, a1r = 0.f, a1i = 0.f;
        float a2r = 0.f, a2i = 0.f, a3r = 0.f, a3i = 0.f;
        const float4* r0 = (const float4*)&xwin[c0][0];
        const float4* r1 = (const float4*)&xwin[c0 + 4][0];
        const float4* r2 = (const float4*)&xwin[c0 + 8][0];
        const float4* r3 = (const float4*)&xwin[c0 + 12][0];

#pragma unroll
        for (int m = 0; m < 4; ++m) {
            int j = (f * m) & 3;                       // seed = (-i)^(f*m), exact
            float cr = (j == 0) ? 1.f : ((j == 2) ? -1.f : 0.f);
            float ci = (j == 1) ? -1.f : ((j == 3) ? 1.f : 0.f);
#pragma unroll
            for (int q4 = 0; q4 < 8; ++q4) {
                int idx = m * 8 + q4;
                float4 x0 = r0[idx], x1 = r1[idx], x2 = r2[idx], x3 = r3[idx];
#define DFT_STEP(e)                                                         \
                {                                                           \
                    float xa = x0.e, xb = x1.e, xc = x2.e, xd = x3.e;       \
                    a0r = fmaf(xa, cr, a0r); a0i = fmaf(xa, ci, a0i);       \
                    a1r = fmaf(xb, cr, a1r); a1i = fmaf(xb, ci, a1i);       \
                    a2r = fmaf(xc, cr, a2r); a2i = fmaf(xc, ci, a2i);       \
                    a3r = fmaf(xd, cr, a3r); a3i = fmaf(xd, ci, a3i);       \
                    float t_ = cr * wr - ci * wi;                           \
                    ci = cr * wi + ci * wr;                                 \
                    cr = t_;                                                \
                }
                DFT_STEP(x) DFT_STEP(y) DFT_STEP(z) DFT_STEP(w)
#undef DFT_STEP
            }
        }
        Xre[c0][fi0]      = a0r;  Xim[c0][fi0]      = a0i;
        Xre[c0 + 4][fi0]  = a1r;  Xim[c0 + 4][fi0]  = a1i;
        Xre[c0 + 8][fi0]  = a2r;  Xim[c0 + 8][fi0]  = a2i;
        Xre[c0 + 12][fi0] = a3r;  Xim[c0 + 12][fi0] = a3i;
        __syncthreads();

        // accumulate Hermitian CSD:  S[c][d] += X_c * conj(X_d)
        for (int i = tid; i < NPAIR * 64; i += 256) {
            int p = i >> 6, fi = i & 63;
            int c = pc_[p], d = pd_[p];
            float xcr = Xre[c][fi], xci = Xim[c][fi];
            float xdr = Xre[d][fi], xdi = Xim[d][fi];
            csd_re[p][fi] += xcr * xdr + xci * xdi;
            csd_im[p][fi] += xci * xdr - xcr * xdi;
        }
        __syncthreads();
    }

    // band averaging: band[k][c][d] = sum_{fi in band} |S|^2 / (256*cnt)
    const int lo[NBAND] = {0, 6, 12, 19, 32, 48};
    const int hi[NBAND] = {6, 12, 19, 32, 48, 64};
    float* bb = band + (size_t)(b * NWIN + w) * (NBAND * 256);
    for (int i = tid; i < NBAND * NPAIR; i += 256) {
        int k = i / NPAIR, p = i - k * NPAIR;
        int c = pc_[p], d = pd_[p];
        float sum = 0.f;
        for (int fi = lo[k]; fi < hi[k]; ++fi) {
            float re = csd_re[p][fi], im = csd_im[p][fi];
            sum += re * re + im * im;
        }
        float val = sum / (256.f * (float)(hi[k] - lo[k]));
        bb[k * 256 + c * 16 + d] = val;
        bb[k * 256 + d * 16 + c] = val;
    }
}

// ---------------------------------------------------------------------------
// Kernel 2: 16x16 symmetric eigendecomposition (fp64 parallel Jacobi,
// tournament ordering) + V * nan_to_num(log(L)) * V^T, transposed write.
// One block (128 thr) per matrix; grid (k, w, b).
// ---------------------------------------------------------------------------
__global__ __launch_bounds__(128) void eig_log_kernel(const float* __restrict__ band,
                                                      float* __restrict__ out)
{
    const int k = blockIdx.x, w = blockIdx.y, b = blockIdx.z;
    const int tid = threadIdx.x;

    __shared__ double A[16][17];
    __shared__ double V[16][17];
    __shared__ double cc[8], ss[8];
    __shared__ int    pp[8], qq[8];
    __shared__ double lv[16];

    const float* M = band + ((size_t)(b * NWIN + w) * NBAND + k) * 256;
    for (int i = tid; i < 256; i += 128) {
        int r = i >> 4, c = i & 15;
        A[r][c] = (double)M[i];
        V[r][c] = (r == c) ? 1.0 : 0.0;
    }
    __syncthreads();

    for (int sweep = 0; sweep < 8; ++sweep) {
        for (int rr = 0; rr < 15; ++rr) {
            if (tid < 8) {
                int p, q;
                if (tid == 0) { p = 15; q = rr % 15; }
                else          { p = (rr + tid) % 15; q = (rr + 15 - tid) % 15; }
                if (p > q) { int t_ = p; p = q; q = t_; }
                double apq = A[p][q];
                double c_ = 1.0, s_ = 0.0;
                if (apq != 0.0) {
                    double tau = (A[q][q] - A[p][p]) / (2.0 * apq);
                    double t   = copysign(1.0, tau) / (fabs(tau) + sqrt(1.0 + tau * tau));
                    c_ = 1.0 / sqrt(1.0 + t * t);
                    s_ = t * c_;
                }
                cc[tid] = c_; ss[tid] = s_; pp[tid] = p; qq[tid] = q;
            }
            __syncthreads();
            {   // row update: A <- J^T A   (128 disjoint tasks: pair j, column n)
                int j = tid >> 4, n = tid & 15;
                int p = pp[j], q = qq[j];
                double c_ = cc[j], s_ = ss[j];
                double ap = A[p][n], aq = A[q][n];
                A[p][n] = c_ * ap - s_ * aq;
                A[q][n] = s_ * ap + c_ * aq;
            }
            __syncthreads();
            {   // col update: A <- A J, V <- V J  (tasks: row i, pair j)
                int j = tid >> 4, i = tid & 15;
                int p = pp[j], q = qq[j];
                double c_ = cc[j], s_ = ss[j];
                double ap = A[i][p], aq = A[i][q];
                A[i][p] = c_ * ap - s_ * aq;
                A[i][q] = s_ * ap + c_ * aq;
                double vp = V[i][p], vq = V[i][q];
                V[i][p] = c_ * vp - s_ * vq;
                V[i][q] = s_ * vp + c_ * vq;
            }
            __syncthreads();
        }
    }

    if (tid < 16) {
        double ev = A[tid][tid];
        double l  = log(ev);
        if (isnan(l) || isinf(l)) l = 0.0;   // nan_to_num(nan=0, neginf=0)
        lv[tid] = l;
    }
    __syncthreads();

    // out[b][k][c][d][w] = sum_e V[c][e] * lv[e] * V[d][e]
    float* ob = out + (size_t)(b * NBAND + k) * 256 * NWIN;
    for (int i = tid; i < 256; i += 128) {
        int c = i >> 4, d = i & 15;
        double sum = 0.0;
#pragma unroll
        for (int e = 0; e < 16; ++e) sum += V[c][e] * lv[e] * V[d][e];
        ob[(size_t)i * NWIN + w] = (float)sum;
    }
}

// ---------------------------------------------------------------------------
extern "C" void kernel_launch(void* const* d_in, const int* in_sizes, int n_in,
                              void* d_out, int out_size, void* d_ws, size_t ws_size,
                              hipStream_t stream)
{
    const float* x   = (const float*)d_in[0];
    float*       out = (float*)d_out;
    float*       band = (float*)d_ws;   // needs 8*252*6*256*4 = 12,386,304 bytes

    dim3 g1(NWIN, NB), b1(256);
    hipLaunchKernelGGL(csd_band_kernel, g1, b1, 0, stream, x, band);

    dim3 g2(NBAND, NWIN, NB), b2(128);
    hipLaunchKernelGGL(eig_log_kernel, g2, b2, 0, stream, band, out);
}

// Round 2
// 814.271 us; speedup vs baseline: 2.4450x; 2.4450x over previous
//
#include <hip/hip_runtime.h>
#include <math.h>

#define T_LEN 32768
#define NCH   16
#define NB    8
#define NWIN  252
#define NBAND 6
#define NPAIR 136

// compile-time upper-triangle pair table (p -> (c,d))
struct PairTab { int c[NPAIR]; int d[NPAIR]; };
constexpr PairTab mkpairs() {
    PairTab P{}; int p = 0;
    for (int c = 0; c < 16; ++c)
        for (int d = c; d < 16; ++d) { P.c[p] = c; P.d[p] = d; ++p; }
    return P;
}
constexpr PairTab PT = mkpairs();

// CSD accumulate for wave-group G: pairs {G, G+8, ..., G+128} (17 pairs).
// All indices compile-time after unroll -> register arrays stay in registers.
template<int G>
__device__ __forceinline__ void acc_csd(const float* __restrict__ Xr,
                                        const float* __restrict__ Xi,
                                        float* __restrict__ sre,
                                        float* __restrict__ sim)
{
#pragma unroll
    for (int t = 0; t < 17; ++t) {
        const int c = PT.c[G + 8 * t];
        const int d = PT.d[G + 8 * t];
        sre[t] = fmaf(Xr[c], Xr[d], sre[t]);
        sre[t] = fmaf(Xi[c], Xi[d], sre[t]);
        sim[t] = fmaf(Xi[c], Xr[d], sim[t]);
        sim[t] = fmaf(-Xr[c], Xi[d], sim[t]);
    }
}

// ---------------------------------------------------------------------------
// Kernel 1: fused STFT + CSD + band averaging. One 512-thread block per (b,w).
// Wave g (0..7) computes DFT of channels {g, g+8} at its lane's freq bin, and
// accumulates CSD pairs {g, g+8k} in registers. Band sums reduced via LDS
// atomics, then written (full symmetric 16x16 per band) to workspace.
// ---------------------------------------------------------------------------
__global__ __launch_bounds__(512, 2) void csd_band_kernel(const float* __restrict__ x,
                                                          float* __restrict__ band)
{
    const int w   = blockIdx.x;   // 0..251
    const int b   = blockIdx.y;   // 0..7
    const int tid = threadIdx.x;
    const int fi  = tid & 63;     // bin-1 (f = fi+1, bins 1..64)
    const int g   = tid >> 6;     // wave id 0..7 (wave-uniform)
    const int f   = fi + 1;

    __shared__ float2 tw[32][64];        // tw[q][fi] = exp(-2*pi*i*f*q/128)  (16 KB)
    __shared__ float  xwin[NCH][128];    // windowed frame                    (8 KB)
    __shared__ float2 X2[NCH][64];       // STFT of current frame             (8 KB)
    __shared__ float  bl[NBAND][NPAIR];  // band |csd|^2 sums                 (3.2 KB)
    __shared__ float  wn[128];
    __shared__ unsigned char pc_[NPAIR], pd_[NPAIR];

    const double PI = 3.14159265358979323846;

    // ---- init: window, twiddle table, band sums, pair tables ----
    if (tid < 128) {
        double ang = 2.0 * PI * (double)tid / 127.0;
        wn[tid] = (float)((0.5 - 0.5 * cos(ang)) / sqrt(47.625)); // ||hann(128)||^2 = 47.625
    }
    for (int idx = tid; idx < 32 * 64; idx += 512) {
        int q = idx >> 6, fj = (idx & 63) + 1;
        double ang = -2.0 * PI * (double)((fj * q) & 127) / 128.0;
        tw[q][idx & 63] = make_float2((float)cos(ang), (float)sin(ang));
    }
    for (int i = tid; i < NBAND * NPAIR; i += 512) (&bl[0][0])[i] = 0.f;
    if (tid < NPAIR) {
        int rem = tid, c = 0;
        while (rem >= 16 - c) { rem -= 16 - c; ++c; }
        pc_[tid] = (unsigned char)c; pd_[tid] = (unsigned char)(c + rem);
    }

    // per-thread CSD accumulators (17 pairs, registers)
    float sre[17], sim[17];
#pragma unroll
    for (int t = 0; t < 17; ++t) { sre[t] = 0.f; sim[t] = 0.f; }

    const float* xb = x + (size_t)(b * NCH) * T_LEN + (size_t)w * 128;

    __syncthreads();

    for (int s = 0; s < 16; ++s) {
        // ---- stage windowed frame (512 float4 = 2048 floats) ----
        {
            int c = tid >> 5, n4 = tid & 31;
            float4 v  = *(const float4*)(xb + (size_t)c * T_LEN + s * 32 + n4 * 4);
            float4 wv = *(const float4*)(&wn[n4 * 4]);
            v.x *= wv.x; v.y *= wv.y; v.z *= wv.z; v.w *= wv.w;
            ((float4*)&xwin[c][0])[n4] = v;
        }
        __syncthreads();

        // ---- DFT: X[f] = sum_a (-i)^(f*a) * sum_q xw[32a+q] * tw[q]  ----
        float X0r = 0.f, X0i = 0.f, X1r = 0.f, X1i = 0.f;
#pragma unroll
        for (int a = 0; a < 4; ++a) {
            float P0r = 0.f, P0i = 0.f, P1r = 0.f, P1i = 0.f;
            const float4* r0 = (const float4*)&xwin[g][a * 32];
            const float4* r1 = (const float4*)&xwin[g + 8][a * 32];
#pragma unroll
            for (int t = 0; t < 8; ++t) {
                float4 x0 = r0[t], x1 = r1[t];
                float2 w0 = tw[t * 4 + 0][fi];
                float2 w1 = tw[t * 4 + 1][fi];
                float2 w2 = tw[t * 4 + 2][fi];
                float2 w3 = tw[t * 4 + 3][fi];
                P0r = fmaf(x0.x, w0.x, P0r); P0i = fmaf(x0.x, w0.y, P0i);
                P1r = fmaf(x1.x, w0.x, P1r); P1i = fmaf(x1.x, w0.y, P1i);
                P0r = fmaf(x0.y, w1.x, P0r); P0i = fmaf(x0.y, w1.y, P0i);
                P1r = fmaf(x1.y, w1.x, P1r); P1i = fmaf(x1.y, w1.y, P1i);
                P0r = fmaf(x0.z, w2.x, P0r); P0i = fmaf(x0.z, w2.y, P0i);
                P1r = fmaf(x1.z, w2.x, P1r); P1i = fmaf(x1.z, w2.y, P1i);
                P0r = fmaf(x0.w, w3.x, P0r); P0i = fmaf(x0.w, w3.y, P0i);
                P1r = fmaf(x1.w, w3.x, P1r); P1i = fmaf(x1.w, w3.y, P1i);
            }
            // multiply by ph_a = (-i)^((f*a)&3) exactly, accumulate
            int j = (f * a) & 3;
            float sr = (j & 2) ? -1.f : 1.f;
            float si = ((j + 1) & 2) ? -1.f : 1.f;
            float u0 = (j & 1) ? P0i : P0r, v0 = (j & 1) ? P0r : P0i;
            float u1 = (j & 1) ? P1i : P1r, v1 = (j & 1) ? P1r : P1i;
            X0r = fmaf(sr, u0, X0r); X0i = fmaf(si, v0, X0i);
            X1r = fmaf(sr, u1, X1r); X1i = fmaf(si, v1, X1i);
        }
        X2[g][fi]     = make_float2(X0r, X0i);
        X2[g + 8][fi] = make_float2(X1r, X1i);
        __syncthreads();

        // ---- CSD accumulate (registers) ----
        float Xr[16], Xi[16];
#pragma unroll
        for (int c = 0; c < 16; ++c) { float2 v = X2[c][fi]; Xr[c] = v.x; Xi[c] = v.y; }
        switch (g) {   // wave-uniform branch
            case 0: acc_csd<0>(Xr, Xi, sre, sim); break;
            case 1: acc_csd<1>(Xr, Xi, sre, sim); break;
            case 2: acc_csd<2>(Xr, Xi, sre, sim); break;
            case 3: acc_csd<3>(Xr, Xi, sre, sim); break;
            case 4: acc_csd<4>(Xr, Xi, sre, sim); break;
            case 5: acc_csd<5>(Xr, Xi, sre, sim); break;
            case 6: acc_csd<6>(Xr, Xi, sre, sim); break;
            default: acc_csd<7>(Xr, Xi, sre, sim); break;
        }
    }

    // ---- band reduction: |S|^2 summed over bins of each band ----
    const int kband = (fi < 6) ? 0 : (fi < 12) ? 1 : (fi < 19) ? 2
                    : (fi < 32) ? 3 : (fi < 48) ? 4 : 5;
#pragma unroll
    for (int t = 0; t < 17; ++t) {
        float vv = fmaf(sre[t], sre[t], sim[t] * sim[t]);
        atomicAdd(&bl[kband][g + 8 * t], vv);
    }
    __syncthreads();

    // ---- write band matrices (scale 1/(256*cnt), symmetric fill) ----
    const float rs[NBAND] = { 1.f/(256.f*6.f), 1.f/(256.f*6.f), 1.f/(256.f*7.f),
                              1.f/(256.f*13.f), 1.f/(256.f*16.f), 1.f/(256.f*16.f) };
    float* bb = band + (size_t)(b * NWIN + w) * (NBAND * 256);
    for (int i = tid; i < NBAND * NPAIR; i += 512) {
        int k = i / NPAIR, p = i - k * NPAIR;
        int c = pc_[p], d = pd_[p];
        float val = bl[k][p] * rs[k];
        bb[k * 256 + c * 16 + d] = val;
        bb[k * 256 + d * 16 + c] = val;
    }
}

// ---------------------------------------------------------------------------
// Kernel 2: 16x16 symmetric eigendecomposition (fp32 parallel Jacobi,
// tournament ordering, 7 sweeps) + V * nan_to_num(log(L)) * V^T.
// One 64-thread (single-wave) block per matrix; barriers are nearly free.
// ---------------------------------------------------------------------------
__device__ __forceinline__ void tourney(int rr, int j, int& p, int& q)
{
    if (j == 0) { p = 15; q = rr; }
    else { p = (rr + j) % 15; q = (rr + 15 - j) % 15; }
    if (p > q) { int t_ = p; p = q; q = t_; }
}

__global__ __launch_bounds__(64) void eig_log_kernel(const float* __restrict__ band,
                                                     float* __restrict__ out)
{
    const int k = blockIdx.x, w = blockIdx.y, b = blockIdx.z;
    const int tid = threadIdx.x;

    __shared__ float A[16][17];
    __shared__ float V[16][17];
    __shared__ float cc[8], ss[8];
    __shared__ float lv[16];

    const float* M = band + ((size_t)(b * NWIN + w) * NBAND + k) * 256;
#pragma unroll
    for (int it = 0; it < 4; ++it) {
        int i = tid + it * 64, r = i >> 4, c = i & 15;
        A[r][c] = M[i];
        V[r][c] = (r == c) ? 1.f : 0.f;
    }
    __syncthreads();

    for (int sweep = 0; sweep < 7; ++sweep) {
        for (int rr = 0; rr < 15; ++rr) {
            if (tid < 8) {
                int p, q; tourney(rr, tid, p, q);
                float apq = A[p][q], c_ = 1.f, s_ = 0.f;
                if (apq != 0.f) {
                    float tau = (A[q][q] - A[p][p]) / (2.f * apq);
                    float t   = copysignf(1.f, tau) / (fabsf(tau) + sqrtf(1.f + tau * tau));
                    c_ = 1.f / sqrtf(1.f + t * t);
                    s_ = t * c_;
                }
                cc[tid] = c_; ss[tid] = s_;
            }
            __syncthreads();
#pragma unroll
            for (int it = 0; it < 2; ++it) {   // rows: A <- J^T A
                int task = tid + it * 64, j = task >> 4, n = task & 15;
                int p, q; tourney(rr, j, p, q);
                float c_ = cc[j], s_ = ss[j];
                float ap = A[p][n], aq = A[q][n];
                A[p][n] = c_ * ap - s_ * aq;
                A[q][n] = s_ * ap + c_ * aq;
            }
            __syncthreads();
#pragma unroll
            for (int it = 0; it < 2; ++it) {   // cols: A <- A J, V <- V J
                int task = tid + it * 64, j = task >> 4, i2 = task & 15;
                int p, q; tourney(rr, j, p, q);
                float c_ = cc[j], s_ = ss[j];
                float ap = A[i2][p], aq = A[i2][q];
                A[i2][p] = c_ * ap - s_ * aq;
                A[i2][q] = s_ * ap + c_ * aq;
                float vp = V[i2][p], vq = V[i2][q];
                V[i2][p] = c_ * vp - s_ * vq;
                V[i2][q] = s_ * vp + c_ * vq;
            }
            __syncthreads();
        }
    }

    if (tid < 16) {
        float l = logf(A[tid][tid]);
        if (isnan(l) || isinf(l)) l = 0.f;   // nan_to_num(nan=0, neginf=0)
        lv[tid] = l;
    }
    __syncthreads();

    // W = V * diag(lv)  (overwrite A)
#pragma unroll
    for (int it = 0; it < 4; ++it) {
        int i = tid + it * 64, r = i >> 4, c = i & 15;
        A[r][c] = V[r][c] * lv[c];
    }
    __syncthreads();

    // out[b][k][c][d][w] = sum_e W[c][e] * V[d][e]
    float* ob = out + (size_t)(b * NBAND + k) * 256 * NWIN;
#pragma unroll
    for (int it = 0; it < 4; ++it) {
        int i = tid + it * 64, c = i >> 4, d = i & 15;
        float sum = 0.f;
#pragma unroll
        for (int e = 0; e < 16; ++e) sum = fmaf(A[c][e], V[d][e], sum);
        ob[(size_t)i * NWIN + w] = sum;
    }
}

// ---------------------------------------------------------------------------
extern "C" void kernel_launch(void* const* d_in, const int* in_sizes, int n_in,
                              void* d_out, int out_size, void* d_ws, size_t ws_size,
                              hipStream_t stream)
{
    const float* x    = (const float*)d_in[0];
    float*       out  = (float*)d_out;
    float*       band = (float*)d_ws;   // 8*252*6*256*4 = 12,386,304 bytes

    dim3 g1(NWIN, NB), b1(512);
    hipLaunchKernelGGL(csd_band_kernel, g1, b1, 0, stream, x, band);

    dim3 g2(NBAND, NWIN, NB), b2(64);
    hipLaunchKernelGGL(eig_log_kernel, g2, b2, 0, stream, band, out);
}

// Round 3
// 634.151 us; speedup vs baseline: 3.1395x; 1.2840x over previous
//
#include <hip/hip_runtime.h>
#include <math.h>

#define T_LEN 32768
#define NCH   16
#define NB    8
#define NWIN  252
#define NBAND 6
#define NPAIR 136

// compile-time upper-triangle pair table (p -> (c,d))
struct PairTab { int c[NPAIR]; int d[NPAIR]; };
constexpr PairTab mkpairs() {
    PairTab P{}; int p = 0;
    for (int c = 0; c < 16; ++c)
        for (int d = c; d < 16; ++d) { P.c[p] = c; P.d[p] = d; ++p; }
    return P;
}
constexpr PairTab PT = mkpairs();

// CSD accumulate for wave-group G: pairs {G, G+8, ..., G+128} (17 pairs).
template<int G>
__device__ __forceinline__ void acc_csd(const float* __restrict__ Xr,
                                        const float* __restrict__ Xi,
                                        float* __restrict__ sre,
                                        float* __restrict__ sim)
{
#pragma unroll
    for (int t = 0; t < 17; ++t) {
        const int c = PT.c[G + 8 * t];
        const int d = PT.d[G + 8 * t];
        sre[t] = fmaf(Xr[c], Xr[d], sre[t]);
        sre[t] = fmaf(Xi[c], Xi[d], sre[t]);
        sim[t] = fmaf(Xi[c], Xr[d], sim[t]);
        sim[t] = fmaf(-Xr[c], Xi[d], sim[t]);
    }
}

// ---------------------------------------------------------------------------
// Kernel 1: fused STFT + CSD + band averaging. One 512-thread block per (b,w).
// DFT: X[f] = sum_{a<8} P_f^a * sum_{q<16} xw[16a+q]*T_f[q]; T_f in registers,
// P_f^a via running complex product re-seeded each frame. No LDS twiddle reads;
// xwin reads are wave-uniform broadcasts (conflict-free).
// ---------------------------------------------------------------------------
__global__ __launch_bounds__(512, 2) void csd_band_kernel(const float* __restrict__ x,
                                                          float* __restrict__ band)
{
    const int w   = blockIdx.x;   // 0..251
    const int b   = blockIdx.y;   // 0..7
    const int tid = threadIdx.x;
    const int fi  = tid & 63;     // bin-1 (f = fi+1, bins 1..64)
    const int g   = tid >> 6;     // wave id 0..7 (wave-uniform)
    const int f   = fi + 1;

    __shared__ float  xwin[NCH][128];    // windowed frame (8 KB)
    __shared__ float2 X2[NCH][64];       // STFT of current frame (8 KB)
    __shared__ float  bl[NBAND][NPAIR];  // band |csd|^2 sums
    __shared__ float  wn[128];
    __shared__ unsigned char pc_[NPAIR], pd_[NPAIR];

    const double PI = 3.14159265358979323846;

    // ---- init ----
    if (tid < 128) {
        double ang = 2.0 * PI * (double)tid / 127.0;
        wn[tid] = (float)((0.5 - 0.5 * cos(ang)) / sqrt(47.625)); // ||hann(128)||^2 = 47.625
    }
    for (int i = tid; i < NBAND * NPAIR; i += 512) (&bl[0][0])[i] = 0.f;
    if (tid < NPAIR) {
        int rem = tid, c = 0;
        while (rem >= 16 - c) { rem -= 16 - c; ++c; }
        pc_[tid] = (unsigned char)c; pd_[tid] = (unsigned char)(c + rem);
    }

    // per-lane register twiddles: T_f[q] = exp(-2*pi*i*f*q/128), q<16
    float twr[16], twi[16];
#pragma unroll
    for (int q = 0; q < 16; ++q) {
        int m = (f * q) & 127;
        float ang = (float)m * -0.04908738521234052f;   // -2*pi/128
        __sincosf(ang, &twi[q], &twr[q]);               // twi=sin, twr=cos
    }
    float Pr, Pi_;
    {
        float ang = (float)(f & 7) * -0.7853981633974483f;  // -2*pi/8
        __sincosf(ang, &Pi_, &Pr);
    }

    // per-thread CSD accumulators (17 pairs)
    float sre[17], sim[17];
#pragma unroll
    for (int t = 0; t < 17; ++t) { sre[t] = 0.f; sim[t] = 0.f; }

    const float* xb = x + (size_t)(b * NCH) * T_LEN + (size_t)w * 128;

    __syncthreads();

    for (int s = 0; s < 16; ++s) {
        // ---- stage windowed frame ----
        {
            int c = tid >> 5, n4 = tid & 31;
            float4 v  = *(const float4*)(xb + (size_t)c * T_LEN + s * 32 + n4 * 4);
            float4 wv = *(const float4*)(&wn[n4 * 4]);
            v.x *= wv.x; v.y *= wv.y; v.z *= wv.z; v.w *= wv.w;
            ((float4*)&xwin[c][0])[n4] = v;
        }
        __syncthreads();

        // ---- DFT for channels g and g+8 at bin f ----
        float X0r = 0.f, X0i = 0.f, X1r = 0.f, X1i = 0.f;
        float pcr = 1.f, pci = 0.f;
#pragma unroll
        for (int a = 0; a < 8; ++a) {
            float A0r = 0.f, A0i = 0.f, A1r = 0.f, A1i = 0.f;
            const float4* p0 = (const float4*)&xwin[g][a * 16];
            const float4* p1 = (const float4*)&xwin[g + 8][a * 16];
#pragma unroll
            for (int k = 0; k < 4; ++k) {
                float4 x0 = p0[k], x1 = p1[k];
#define DFT_E(e, qq)                                                  \
                A0r = fmaf(x0.e, twr[qq], A0r); A0i = fmaf(x0.e, twi[qq], A0i); \
                A1r = fmaf(x1.e, twr[qq], A1r); A1i = fmaf(x1.e, twi[qq], A1i);
                DFT_E(x, 4*k+0) DFT_E(y, 4*k+1) DFT_E(z, 4*k+2) DFT_E(w, 4*k+3)
#undef DFT_E
            }
            // X += pc * A  (pc = P^a)
            X0r = fmaf(pcr, A0r, X0r); X0r = fmaf(-pci, A0i, X0r);
            X0i = fmaf(pcr, A0i, X0i); X0i = fmaf(pci, A0r, X0i);
            X1r = fmaf(pcr, A1r, X1r); X1r = fmaf(-pci, A1i, X1r);
            X1i = fmaf(pcr, A1i, X1i); X1i = fmaf(pci, A1r, X1i);
            // pc *= P
            float tt = pcr * Pr - pci * Pi_;
            pci = fmaf(pcr, Pi_, pci * Pr);
            pcr = tt;
        }
        X2[g][fi]     = make_float2(X0r, X0i);
        X2[g + 8][fi] = make_float2(X1r, X1i);
        __syncthreads();

        // ---- CSD accumulate (registers) ----
        float Xr[16], Xi[16];
#pragma unroll
        for (int c = 0; c < 16; ++c) { float2 v = X2[c][fi]; Xr[c] = v.x; Xi[c] = v.y; }
        switch (g) {
            case 0: acc_csd<0>(Xr, Xi, sre, sim); break;
            case 1: acc_csd<1>(Xr, Xi, sre, sim); break;
            case 2: acc_csd<2>(Xr, Xi, sre, sim); break;
            case 3: acc_csd<3>(Xr, Xi, sre, sim); break;
            case 4: acc_csd<4>(Xr, Xi, sre, sim); break;
            case 5: acc_csd<5>(Xr, Xi, sre, sim); break;
            case 6: acc_csd<6>(Xr, Xi, sre, sim); break;
            default: acc_csd<7>(Xr, Xi, sre, sim); break;
        }
    }

    // ---- band reduction ----
    const int kband = (fi < 6) ? 0 : (fi < 12) ? 1 : (fi < 19) ? 2
                    : (fi < 32) ? 3 : (fi < 48) ? 4 : 5;
#pragma unroll
    for (int t = 0; t < 17; ++t) {
        float vv = fmaf(sre[t], sre[t], sim[t] * sim[t]);
        atomicAdd(&bl[kband][g + 8 * t], vv);
    }
    __syncthreads();

    const float rs[NBAND] = { 1.f/(256.f*6.f), 1.f/(256.f*6.f), 1.f/(256.f*7.f),
                              1.f/(256.f*13.f), 1.f/(256.f*16.f), 1.f/(256.f*16.f) };
    float* bb = band + (size_t)(b * NWIN + w) * (NBAND * 256);
    for (int i = tid; i < NBAND * NPAIR; i += 512) {
        int k = i / NPAIR, p = i - k * NPAIR;
        int c = pc_[p], d = pd_[p];
        float val = bl[k][p] * rs[k];
        bb[k * 256 + c * 16 + d] = val;
        bb[k * 256 + d * 16 + c] = val;
    }
}

// ---------------------------------------------------------------------------
// Kernel 2: 16x16 symmetric eigendecomposition, fp32 parallel Jacobi
// (tournament ordering, 5 sweeps), via two ROW-updates per rotation using
// symmetry:  DT = (J^T A)^T-stored = A*J, then A' = J^T * DT.  V kept
// transposed so V <- V*J is also a row update. All row accesses are float2.
// One 64-thread (single-wave) block per matrix.
// ---------------------------------------------------------------------------
__device__ __forceinline__ void tourney(int rr, int j, int& p, int& q)
{
    if (j == 0) { p = 15; q = rr; }
    else { p = (rr + j) % 15; q = (rr + 15 - j) % 15; }
    if (p > q) { int t_ = p; p = q; q = t_; }
}

__global__ __launch_bounds__(64) void eig_log_kernel(const float* __restrict__ band,
                                                     float* __restrict__ out)
{
    const int k = blockIdx.x, w = blockIdx.y, b = blockIdx.z;
    const int tid = threadIdx.x;
    const int j   = tid >> 3;   // pair 0..7
    const int n2  = tid & 7;    // column-pair 0..7

    __shared__ float A[16][18];
    __shared__ float DT[16][18];
    __shared__ float VT[16][18];
    __shared__ float csx[8], sx[8];
    __shared__ float lv[16];

    const float* M = band + ((size_t)(b * NWIN + w) * NBAND + k) * 256;
#pragma unroll
    for (int it = 0; it < 4; ++it) {
        int i = tid + it * 64, r = i >> 4, c = i & 15;
        A[r][c]  = M[i];
        VT[r][c] = (r == c) ? 1.f : 0.f;
    }
    __syncthreads();

    for (int sweep = 0; sweep < 5; ++sweep) {
        for (int rr = 0; rr < 15; ++rr) {
            int p, q; tourney(rr, j, p, q);
            // ---- phase A: c,s from A; DT = A*J (i.e. J^T A stored transposed)
            float app = A[p][p], aqq = A[q][q], apq = A[p][q];
            float c_ = 1.f, s_ = 0.f;
            if (apq != 0.f) {
                float tau = (aqq - app) / (2.f * apq);
                float t   = copysignf(1.f, tau) / (fabsf(tau) + sqrtf(1.f + tau * tau));
                c_ = 1.f / sqrtf(1.f + t * t);
                s_ = t * c_;
            }
            csx[j] = c_; sx[j] = s_;   // 8 lanes write same value: benign
            float2 ap = *(const float2*)&A[p][2 * n2];
            float2 aq = *(const float2*)&A[q][2 * n2];
            DT[2 * n2][p]     = c_ * ap.x - s_ * aq.x;
            DT[2 * n2 + 1][p] = c_ * ap.y - s_ * aq.y;
            DT[2 * n2][q]     = s_ * ap.x + c_ * aq.x;
            DT[2 * n2 + 1][q] = s_ * ap.y + c_ * aq.y;
            __syncthreads();

            // ---- phase B: A' = J^T * DT ; VT' = J^T * VT ----
            float c2 = csx[j], s2 = sx[j];
            float2 dp = *(const float2*)&DT[p][2 * n2];
            float2 dq = *(const float2*)&DT[q][2 * n2];
            *(float2*)&A[p][2 * n2] = make_float2(c2 * dp.x - s2 * dq.x,
                                                  c2 * dp.y - s2 * dq.y);
            *(float2*)&A[q][2 * n2] = make_float2(s2 * dp.x + c2 * dq.x,
                                                  s2 * dp.y + c2 * dq.y);
            float2 vp = *(const float2*)&VT[p][2 * n2];
            float2 vq = *(const float2*)&VT[q][2 * n2];
            *(float2*)&VT[p][2 * n2] = make_float2(c2 * vp.x - s2 * vq.x,
                                                   c2 * vp.y - s2 * vq.y);
            *(float2*)&VT[q][2 * n2] = make_float2(s2 * vp.x + c2 * vq.x,
                                                   s2 * vp.y + c2 * vq.y);
            __syncthreads();
        }
    }

    if (tid < 16) {
        float l = logf(A[tid][tid]);
        if (isnan(l) || isinf(l)) l = 0.f;   // nan_to_num(nan=0, neginf=0)
        lv[tid] = l;
    }
    __syncthreads();

    // out[b][k][c][d][w] = sum_e VT[e][c] * lv[e] * VT[e][d]
    float* ob = out + (size_t)(b * NBAND + k) * 256 * NWIN;
#pragma unroll
    for (int it = 0; it < 4; ++it) {
        int i = tid + it * 64, c = i >> 4, d = i & 15;
        float sum = 0.f;
#pragma unroll
        for (int e = 0; e < 16; ++e) sum = fmaf(VT[e][c] * lv[e], VT[e][d], sum);
        ob[(size_t)i * NWIN + w] = sum;
    }
}

// ---------------------------------------------------------------------------
extern "C" void kernel_launch(void* const* d_in, const int* in_sizes, int n_in,
                              void* d_out, int out_size, void* d_ws, size_t ws_size,
                              hipStream_t stream)
{
    const float* x    = (const float*)d_in[0];
    float*       out  = (float*)d_out;
    float*       band = (float*)d_ws;   // 8*252*6*256*4 = 12,386,304 bytes

    dim3 g1(NWIN, NB), b1(512);
    hipLaunchKernelGGL(csd_band_kernel, g1, b1, 0, stream, x, band);

    dim3 g2(NBAND, NWIN, NB), b2(64);
    hipLaunchKernelGGL(eig_log_kernel, g2, b2, 0, stream, band, out);
}

// Round 4
// 404.563 us; speedup vs baseline: 4.9211x; 1.5675x over previous
//
#include <hip/hip_runtime.h>
#include <math.h>

#define T_LEN 32768
#define NCH   16
#define NB    8
#define NWIN  252
#define NBAND 6
#define NPAIR 136

// compile-time upper-triangle pair table (p -> (c,d))
struct PairTab { int c[NPAIR]; int d[NPAIR]; };
constexpr PairTab mkpairs() {
    PairTab P{}; int p = 0;
    for (int c = 0; c < 16; ++c)
        for (int d = c; d < 16; ++d) { P.c[p] = c; P.d[p] = d; ++p; }
    return P;
}
constexpr PairTab PT = mkpairs();

// CSD accumulate for wave-group G: pairs {G, G+8, ..., G+128} (17 pairs).
template<int G>
__device__ __forceinline__ void acc_csd(const float* __restrict__ Xr,
                                        const float* __restrict__ Xi,
                                        float* __restrict__ sre,
                                        float* __restrict__ sim)
{
#pragma unroll
    for (int t = 0; t < 17; ++t) {
        const int c = PT.c[G + 8 * t];
        const int d = PT.d[G + 8 * t];
        sre[t] = fmaf(Xr[c], Xr[d], sre[t]);
        sre[t] = fmaf(Xi[c], Xi[d], sre[t]);
        sim[t] = fmaf(Xi[c], Xr[d], sim[t]);
        sim[t] = fmaf(-Xr[c], Xi[d], sim[t]);
    }
}

// cross-lane exchange helpers
#define SWZ(v, imm)  __int_as_float(__builtin_amdgcn_ds_swizzle(__float_as_int(v), (imm)))
#define DPPQ(v, ctl) __int_as_float(__builtin_amdgcn_mov_dpp(__float_as_int(v), (ctl), 0xF, 0xF, true))

// radix-2 DIF butterfly on one complex value (vr,vi): partner via EX (xor S),
// top lanes (lane&S==0): v+p ; bottom: (p-v)*tw.  tw preloaded per lane
// ( (1,0) on top lanes ), sg_ = +1 top / -1 bottom.
#define BF(vr, vi, EX, twr_, twi_, sg_)                        \
    { float pr_ = EX(vr), pi_ = EX(vi);                        \
      float tr_ = fmaf(sg_, vr, pr_);                          \
      float ti_ = fmaf(sg_, vi, pi_);                          \
      vr = fmaf(tr_, twr_, -(ti_ * twi_));                     \
      vi = fmaf(tr_, twi_,  (ti_ * twr_)); }

// ---------------------------------------------------------------------------
// Kernel 1: fused STFT + CSD + band averaging. One 512-thread block per (b,w).
// Per wave g: channels g and g+8 packed as one complex 128-pt sequence,
// FFT'd across 64 lanes (2 elems/lane, DIF; xor32 bpermute, xor16/8/4
// ds_swizzle, xor2/1 DPP). Real untangle via per-wave LDS scratch with
// bit-reversal folded into gather addresses. No frame staging in LDS.
// ---------------------------------------------------------------------------
__global__ __launch_bounds__(512, 2) void csd_band_kernel(const float* __restrict__ x,
                                                          float* __restrict__ band)
{
    const int w    = blockIdx.x;
    const int b    = blockIdx.y;
    const int tid  = threadIdx.x;
    const int lane = tid & 63;
    const int g    = tid >> 6;     // wave id 0..7
    const int f    = lane + 1;     // this lane's output bin (1..64)

    __shared__ float2 X2[NCH][64];       // per-frame STFT exchange (8 KB)
    __shared__ float2 scr[8][2][64];     // per-wave untangle scratch (8 KB)
    __shared__ float  bl[NBAND][NPAIR];  // band |csd|^2 sums
    __shared__ unsigned char pc_[NPAIR], pd_[NPAIR];

    // ---- init ----
    for (int i = tid; i < NBAND * NPAIR; i += 512) (&bl[0][0])[i] = 0.f;
    if (tid < NPAIR) {
        int rem = tid, c = 0;
        while (rem >= 16 - c) { rem -= 16 - c; ++c; }
        pc_[tid] = (unsigned char)c; pd_[tid] = (unsigned char)(c + rem);
    }

    // window (incl. 1/||w||): hanning(128)[n] = .5-.5cos(2*pi*n/127), ||w||^2=47.625
    const double PI = 3.14159265358979323846;
    const float  WI = (float)(1.0 / sqrt(47.625));
    const float wlo = (float)(0.5 - 0.5 * cos(2.0 * PI * (double)lane / 127.0)) * WI;
    const float whi = (float)(0.5 - 0.5 * cos(2.0 * PI * (double)(lane + 64) / 127.0)) * WI;

    // FFT twiddles (per lane, computed once)
    const float PIF = 3.14159265358979f;
    float w128r, w128i;  // stage span=64: W128^lane
    { float a = -2.f * PIF * (float)lane / 128.f; sincosf(a, &w128i, &w128r); }
    float t32r, t32i, t16r, t16i, t8r, t8i, t4r, t4i, t2r, t2i;
    { float a = (lane & 32) ? -2.f * PIF * (float)(lane & 31) / 64.f : 0.f; sincosf(a, &t32i, &t32r); }
    { float a = (lane & 16) ? -2.f * PIF * (float)(lane & 15) / 32.f : 0.f; sincosf(a, &t16i, &t16r); }
    { float a = (lane &  8) ? -2.f * PIF * (float)(lane &  7) / 16.f : 0.f; sincosf(a, &t8i,  &t8r ); }
    { float a = (lane &  4) ? -2.f * PIF * (float)(lane &  3) /  8.f : 0.f; sincosf(a, &t4i,  &t4r ); }
    { float a = (lane &  2) ? -2.f * PIF * (float)(lane &  1) /  4.f : 0.f; sincosf(a, &t2i,  &t2r ); }
    const float sg32 = (lane & 32) ? -1.f : 1.f;
    const float sg16 = (lane & 16) ? -1.f : 1.f;
    const float sg8  = (lane &  8) ? -1.f : 1.f;
    const float sg4  = (lane &  4) ? -1.f : 1.f;
    const float sg2  = (lane &  2) ? -1.f : 1.f;
    const float sg1  = (lane &  1) ? -1.f : 1.f;

    const int bp32 = 4 * (lane ^ 32);                          // bpermute addr, xor32
    // untangle gather: U[k] lives at slot k&1, lane bitrev6(k>>1)
    const int La = (int)(__brev((unsigned)(f >> 1)) >> 26);          // U[f]
    const int Lb = (int)(__brev((unsigned)((128 - f) >> 1)) >> 26);  // U[128-f]
    const int pa = f & 1;                                            // same parity for both

    // per-thread CSD accumulators (17 pairs)
    float sre[17], sim[17];
#pragma unroll
    for (int t = 0; t < 17; ++t) { sre[t] = 0.f; sim[t] = 0.f; }

    const float* xp0 = x + (size_t)(b * NCH + g) * T_LEN + (size_t)w * 128;
    const float* xp1 = xp0 + 8 * (size_t)T_LEN;

    __syncthreads();

    for (int s = 0; s < 16; ++s) {
        // ---- load + window + pack: u = xw_g + i*xw_{g+8} ; slot0=u[lane], slot1=u[lane+64]
        float s0r = xp0[s * 32 + lane]      * wlo;
        float s1r = xp0[s * 32 + lane + 64] * whi;
        float s0i = xp1[s * 32 + lane]      * wlo;
        float s1i = xp1[s * 32 + lane + 64] * whi;

        // ---- stage span=64 (in-lane): slot0=a+b, slot1=(a-b)*W128^lane
        {
            float dr = s0r - s1r, di = s0i - s1i;
            s0r += s1r; s0i += s1i;
            float nr = fmaf(dr, w128r, -(di * w128i));
            s1i = fmaf(dr, w128i, di * w128r);
            s1r = nr;
        }
        // ---- stages span 32..1 across lanes (both slots independent 64-pt FFTs)
#define EX32(v) __int_as_float(__builtin_amdgcn_ds_bpermute(bp32, __float_as_int(v)))
#define EX16(v) SWZ(v, 0x401F)
#define EX8(v)  SWZ(v, 0x201F)
#define EX4(v)  SWZ(v, 0x101F)
#define EX2(v)  DPPQ(v, 0x4E)   // quad_perm [2,3,0,1] = xor2
#define EX1(v)  DPPQ(v, 0xB1)   // quad_perm [1,0,3,2] = xor1
        BF(s0r, s0i, EX32, t32r, t32i, sg32)
        BF(s1r, s1i, EX32, t32r, t32i, sg32)
        BF(s0r, s0i, EX16, t16r, t16i, sg16)
        BF(s1r, s1i, EX16, t16r, t16i, sg16)
        BF(s0r, s0i, EX8,  t8r,  t8i,  sg8)
        BF(s1r, s1i, EX8,  t8r,  t8i,  sg8)
        BF(s0r, s0i, EX4,  t4r,  t4i,  sg4)
        BF(s1r, s1i, EX4,  t4r,  t4i,  sg4)
        BF(s0r, s0i, EX2,  t2r,  t2i,  sg2)
        BF(s1r, s1i, EX2,  t2r,  t2i,  sg2)
        {   // last stage span=1: no twiddle
            float pr = EX1(s0r), pi = EX1(s0i);
            s0r = fmaf(sg1, s0r, pr); s0i = fmaf(sg1, s0i, pi);
        }
        {
            float pr = EX1(s1r), pi = EX1(s1i);
            s1r = fmaf(sg1, s1r, pr); s1i = fmaf(sg1, s1i, pi);
        }

        // ---- untangle via per-wave scratch (wave-synchronous, no barrier)
        scr[g][0][lane] = make_float2(s0r, s0i);
        scr[g][1][lane] = make_float2(s1r, s1i);
        float2 Ua = scr[g][pa][La];   // U[f]
        float2 Ub = scr[g][pa][Lb];   // U[128-f]
        // X_g[f]    = (U + conj(Ub))/2 ; X_{g+8}[f] = (U - conj(Ub))/(2i)
        float X0r = 0.5f * (Ua.x + Ub.x), X0i = 0.5f * (Ua.y - Ub.y);
        float X1r = 0.5f * (Ua.y + Ub.y), X1i = 0.5f * (Ub.x - Ua.x);

        __syncthreads();   // all waves done reading previous frame's X2
        X2[g][lane]     = make_float2(X0r, X0i);
        X2[g + 8][lane] = make_float2(X1r, X1i);
        __syncthreads();

        // ---- CSD accumulate (registers) ----
        float Xr[16], Xi[16];
#pragma unroll
        for (int c = 0; c < 16; ++c) { float2 v = X2[c][lane]; Xr[c] = v.x; Xi[c] = v.y; }
        switch (g) {
            case 0: acc_csd<0>(Xr, Xi, sre, sim); break;
            case 1: acc_csd<1>(Xr, Xi, sre, sim); break;
            case 2: acc_csd<2>(Xr, Xi, sre, sim); break;
            case 3: acc_csd<3>(Xr, Xi, sre, sim); break;
            case 4: acc_csd<4>(Xr, Xi, sre, sim); break;
            case 5: acc_csd<5>(Xr, Xi, sre, sim); break;
            case 6: acc_csd<6>(Xr, Xi, sre, sim); break;
            default: acc_csd<7>(Xr, Xi, sre, sim); break;
        }
    }

    // ---- band reduction: |S|^2 summed over bins of each band ----
    const int kband = (lane < 6) ? 0 : (lane < 12) ? 1 : (lane < 19) ? 2
                    : (lane < 32) ? 3 : (lane < 48) ? 4 : 5;
#pragma unroll
    for (int t = 0; t < 17; ++t) {
        float vv = fmaf(sre[t], sre[t], sim[t] * sim[t]);
        atomicAdd(&bl[kband][g + 8 * t], vv);
    }
    __syncthreads();

    const float rs[NBAND] = { 1.f/(256.f*6.f), 1.f/(256.f*6.f), 1.f/(256.f*7.f),
                              1.f/(256.f*13.f), 1.f/(256.f*16.f), 1.f/(256.f*16.f) };
    float* bb = band + (size_t)(b * NWIN + w) * (NBAND * 256);
    for (int i = tid; i < NBAND * NPAIR; i += 512) {
        int k = i / NPAIR, p = i - k * NPAIR;
        int c = pc_[p], d = pd_[p];
        float val = bl[k][p] * rs[k];
        bb[k * 256 + c * 16 + d] = val;
        bb[k * 256 + d * 16 + c] = val;
    }
}

// ---------------------------------------------------------------------------
// Kernel 2: 16x16 symmetric eigendecomposition, fp32 parallel Jacobi
// (tournament ordering, 5 sweeps), two row-updates per rotation via symmetry.
// One 64-thread (single-wave) block per matrix.
// ---------------------------------------------------------------------------
__device__ __forceinline__ void tourney(int rr, int j, int& p, int& q)
{
    if (j == 0) { p = 15; q = rr; }
    else { p = (rr + j) % 15; q = (rr + 15 - j) % 15; }
    if (p > q) { int t_ = p; p = q; q = t_; }
}

__global__ __launch_bounds__(64) void eig_log_kernel(const float* __restrict__ band,
                                                     float* __restrict__ out)
{
    const int k = blockIdx.x, w = blockIdx.y, b = blockIdx.z;
    const int tid = threadIdx.x;
    const int j   = tid >> 3;   // pair 0..7
    const int n2  = tid & 7;    // column-pair 0..7

    __shared__ float A[16][18];
    __shared__ float DT[16][18];
    __shared__ float VT[16][18];
    __shared__ float csx[8], sx[8];
    __shared__ float lv[16];

    const float* M = band + ((size_t)(b * NWIN + w) * NBAND + k) * 256;
#pragma unroll
    for (int it = 0; it < 4; ++it) {
        int i = tid + it * 64, r = i >> 4, c = i & 15;
        A[r][c]  = M[i];
        VT[r][c] = (r == c) ? 1.f : 0.f;
    }
    __syncthreads();

    for (int sweep = 0; sweep < 5; ++sweep) {
        for (int rr = 0; rr < 15; ++rr) {
            int p, q; tourney(rr, j, p, q);
            float app = A[p][p], aqq = A[q][q], apq = A[p][q];
            float c_ = 1.f, s_ = 0.f;
            if (apq != 0.f) {
                float tau = (aqq - app) / (2.f * apq);
                float t   = copysignf(1.f, tau) / (fabsf(tau) + sqrtf(1.f + tau * tau));
                c_ = 1.f / sqrtf(1.f + t * t);
                s_ = t * c_;
            }
            csx[j] = c_; sx[j] = s_;
            float2 ap = *(const float2*)&A[p][2 * n2];
            float2 aq = *(const float2*)&A[q][2 * n2];
            DT[2 * n2][p]     = c_ * ap.x - s_ * aq.x;
            DT[2 * n2 + 1][p] = c_ * ap.y - s_ * aq.y;
            DT[2 * n2][q]     = s_ * ap.x + c_ * aq.x;
            DT[2 * n2 + 1][q] = s_ * ap.y + c_ * aq.y;
            __syncthreads();

            float c2 = csx[j], s2 = sx[j];
            float2 dp = *(const float2*)&DT[p][2 * n2];
            float2 dq = *(const float2*)&DT[q][2 * n2];
            *(float2*)&A[p][2 * n2] = make_float2(c2 * dp.x - s2 * dq.x,
                                                  c2 * dp.y - s2 * dq.y);
            *(float2*)&A[q][2 * n2] = make_float2(s2 * dp.x + c2 * dq.x,
                                                  s2 * dp.y + c2 * dq.y);
            float2 vp = *(const float2*)&VT[p][2 * n2];
            float2 vq = *(const float2*)&VT[q][2 * n2];
            *(float2*)&VT[p][2 * n2] = make_float2(c2 * vp.x - s2 * vq.x,
                                                   c2 * vp.y - s2 * vq.y);
            *(float2*)&VT[q][2 * n2] = make_float2(s2 * vp.x + c2 * vq.x,
                                                   s2 * vp.y + c2 * vq.y);
            __syncthreads();
        }
    }

    if (tid < 16) {
        float l = logf(A[tid][tid]);
        if (isnan(l) || isinf(l)) l = 0.f;
        lv[tid] = l;
    }
    __syncthreads();

    float* ob = out + (size_t)(b * NBAND + k) * 256 * NWIN;
#pragma unroll
    for (int it = 0; it < 4; ++it) {
        int i = tid + it * 64, c = i >> 4, d = i & 15;
        float sum = 0.f;
#pragma unroll
        for (int e = 0; e < 16; ++e) sum = fmaf(VT[e][c] * lv[e], VT[e][d], sum);
        ob[(size_t)i * NWIN + w] = sum;
    }
}

// ---------------------------------------------------------------------------
extern "C" void kernel_launch(void* const* d_in, const int* in_sizes, int n_in,
                              void* d_out, int out_size, void* d_ws, size_t ws_size,
                              hipStream_t stream)
{
    const float* x    = (const float*)d_in[0];
    float*       out  = (float*)d_out;
    float*       band = (float*)d_ws;   // 8*252*6*256*4 = 12,386,304 bytes

    dim3 g1(NWIN, NB), b1(512);
    hipLaunchKernelGGL(csd_band_kernel, g1, b1, 0, stream, x, band);

    dim3 g2(NBAND, NWIN, NB), b2(64);
    hipLaunchKernelGGL(eig_log_kernel, g2, b2, 0, stream, band, out);
}